// Round 4
// baseline (77.750 us; speedup 1.0000x reference)
//
#include <hip/hip_runtime.h>

#define Q 4096
#define L 8192
#define NCB 2048               // ctx blocks in K1: 4 rows each
#define RPB 4                  // rows per ctx block
#define NKB 1024               // Kw-half blocks in K1: 4 rows each (1 row/wave)

// async global->LDS copy, 16B per lane (DMA, no VGPR round trip)
__device__ __forceinline__ void ld_g2l16(const float* gp, float* lp) {
    __builtin_amdgcn_global_load_lds(
        (const __attribute__((address_space(1))) void*)gp,
        (__attribute__((address_space(3))) void*)lp,
        16, 0, 0);
}

// ---------------------------------------------------------------------------
// K1, blocks 0..NCB-1: stage 4 ctx rows in LDS, wave-per-row dot (no block
//   barrier), local softmax over the 4 scores, weighted accumulate -> partial.
//   Writes RAW scores to score[] (K2 reconstructs everything from them).
// K1, blocks NCB..NCB+NKB-1: out1[i] = Kw[i, 0:Q] . q, one wave per row,
//   barrier-free.
// ---------------------------------------------------------------------------
__global__ __launch_bounds__(256) void k1_kernel(
    const float* __restrict__ qvec, const float* __restrict__ ctx,
    const float* __restrict__ Kw, float* __restrict__ partial,
    float* __restrict__ score, float* __restrict__ out1)
{
    __shared__ float rows[RPB * Q];   // 64 KB
    __shared__ float sc[RPB];
    const int tid  = threadIdx.x;
    const int lane = tid & 63;
    const int wid  = tid >> 6;

    if (blockIdx.x < NCB) {
        // ---- stage 4 consecutive rows (contiguous 64 KB) via DMA ----
        const float* gbase = ctx + (size_t)blockIdx.x * RPB * Q;
        #pragma unroll
        for (int k = 0; k < 16; ++k) {
            const int idx4 = tid + k * 256;              // float4 index
            ld_g2l16(gbase + (size_t)idx4 * 4, rows + (size_t)idx4 * 4);
        }
        __syncthreads();   // drains vmcnt(0): rows ready

        // ---- wave w dots row w against q (q from global: coalesced, L2-hot)
        {
            const float4* __restrict__ rl = (const float4*)(rows) + wid * (Q / 4);
            const float4* __restrict__ qg = (const float4*)qvec;
            float a0 = 0.f, a1 = 0.f;
            #pragma unroll
            for (int c = 0; c < 16; c += 2) {
                float4 x0 = rl[(c + 0) * 64 + lane], y0 = qg[(c + 0) * 64 + lane];
                float4 x1 = rl[(c + 1) * 64 + lane], y1 = qg[(c + 1) * 64 + lane];
                a0 = fmaf(x0.x, y0.x, a0); a0 = fmaf(x0.y, y0.y, a0);
                a0 = fmaf(x0.z, y0.z, a0); a0 = fmaf(x0.w, y0.w, a0);
                a1 = fmaf(x1.x, y1.x, a1); a1 = fmaf(x1.y, y1.y, a1);
                a1 = fmaf(x1.z, y1.z, a1); a1 = fmaf(x1.w, y1.w, a1);
            }
            float d = a0 + a1;
            #pragma unroll
            for (int off = 32; off > 0; off >>= 1) d += __shfl_down(d, off, 64);
            if (lane == 0) {
                sc[wid] = d;
                score[blockIdx.x * RPB + wid] = d;       // raw score for K2
            }
        }
        __syncthreads();

        // ---- local softmax weights over this block's 4 rows ----
        const float s0 = sc[0], s1 = sc[1], s2 = sc[2], s3 = sc[3];
        const float mb = fmaxf(fmaxf(s0, s1), fmaxf(s2, s3));
        const float w0 = __expf(s0 - mb), w1 = __expf(s1 - mb);
        const float w2 = __expf(s2 - mb), w3 = __expf(s3 - mb);

        // ---- weighted accumulate: thread owns float4 cols {tid + k*256} ----
        const float4* __restrict__ r4 = (const float4*)rows;
        float4* __restrict__ pb = (float4*)(partial + (size_t)blockIdx.x * Q);
        #pragma unroll
        for (int k = 0; k < 4; ++k) {
            const int c4 = tid + k * 256;
            float4 v0 = r4[c4];
            float4 v1 = r4[1024 + c4];
            float4 v2 = r4[2048 + c4];
            float4 v3 = r4[3072 + c4];
            float4 a;
            a.x = fmaf(w3, v3.x, fmaf(w2, v2.x, fmaf(w1, v1.x, w0 * v0.x)));
            a.y = fmaf(w3, v3.y, fmaf(w2, v2.y, fmaf(w1, v1.y, w0 * v0.y)));
            a.z = fmaf(w3, v3.z, fmaf(w2, v2.z, fmaf(w1, v1.z, w0 * v0.z)));
            a.w = fmaf(w3, v3.w, fmaf(w2, v2.w, fmaf(w1, v1.w, w0 * v0.w)));
            pb[c4] = a;
        }
    } else {
        // ---- out1[i] = Kw[i, 0:Q] . q : one wave per row, no barriers ----
        const int i = (blockIdx.x - NCB) * 4 + wid;      // 0..4095
        const float4* __restrict__ row = (const float4*)(Kw + (size_t)i * (2 * Q));
        const float4* __restrict__ qg  = (const float4*)qvec;
        float a0 = 0.f, a1 = 0.f, a2 = 0.f, a3 = 0.f;
        #pragma unroll
        for (int c = 0; c < 16; c += 4) {
            float4 x0 = row[(c + 0) * 64 + lane], y0 = qg[(c + 0) * 64 + lane];
            float4 x1 = row[(c + 1) * 64 + lane], y1 = qg[(c + 1) * 64 + lane];
            float4 x2 = row[(c + 2) * 64 + lane], y2 = qg[(c + 2) * 64 + lane];
            float4 x3 = row[(c + 3) * 64 + lane], y3 = qg[(c + 3) * 64 + lane];
            a0 = fmaf(x0.x, y0.x, a0); a0 = fmaf(x0.y, y0.y, a0);
            a0 = fmaf(x0.z, y0.z, a0); a0 = fmaf(x0.w, y0.w, a0);
            a1 = fmaf(x1.x, y1.x, a1); a1 = fmaf(x1.y, y1.y, a1);
            a1 = fmaf(x1.z, y1.z, a1); a1 = fmaf(x1.w, y1.w, a1);
            a2 = fmaf(x2.x, y2.x, a2); a2 = fmaf(x2.y, y2.y, a2);
            a2 = fmaf(x2.z, y2.z, a2); a2 = fmaf(x2.w, y2.w, a2);
            a3 = fmaf(x3.x, y3.x, a3); a3 = fmaf(x3.y, y3.y, a3);
            a3 = fmaf(x3.z, y3.z, a3); a3 = fmaf(x3.w, y3.w, a3);
        }
        float d = (a0 + a1) + (a2 + a3);
        #pragma unroll
        for (int off = 32; off > 0; off >>= 1) d += __shfl_down(d, off, 64);
        if (lane == 0) out1[i] = d;
    }
}

// ---------------------------------------------------------------------------
// K2: global softmax from raw scores + merge NCB partials -> s_t.
//   s_t[j] = (1/Z) * sum_b exp(m_b - M) * partial[b][j],
//   m_b = max(score[4b..4b+3]), M = global max, Z = sum exp(score - M).
// ---------------------------------------------------------------------------
__global__ __launch_bounds__(256) void k2_kernel(
    const float* __restrict__ partial, const float* __restrict__ score,
    float* __restrict__ s_t)
{
    __shared__ float wb[NCB];           // 8 KB
    __shared__ float red[4];
    __shared__ float4 sacc[64][4];      // 4 KB
    const int tid  = threadIdx.x;
    const int lane = tid & 63;
    const int wid  = tid >> 6;

    // global max M
    float lm = -3.4e38f;
    for (int i = tid; i < L; i += 256) lm = fmaxf(lm, score[i]);
    #pragma unroll
    for (int off = 32; off > 0; off >>= 1) lm = fmaxf(lm, __shfl_down(lm, off, 64));
    if (lane == 0) red[wid] = lm;
    __syncthreads();
    const float M = fmaxf(fmaxf(red[0], red[1]), fmaxf(red[2], red[3]));
    __syncthreads();

    // Z
    float lz = 0.f;
    for (int i = tid; i < L; i += 256) lz += __expf(score[i] - M);
    #pragma unroll
    for (int off = 32; off > 0; off >>= 1) lz += __shfl_down(lz, off, 64);
    if (lane == 0) red[wid] = lz;
    __syncthreads();
    const float invZ = 1.f / (red[0] + red[1] + red[2] + red[3]);

    // per-block weights
    for (int b = tid; b < NCB; b += 256) {
        const float4 s4 = ((const float4*)score)[b];
        const float mb = fmaxf(fmaxf(s4.x, s4.y), fmaxf(s4.z, s4.w));
        wb[b] = __expf(mb - M);
    }
    __syncthreads();

    // weighted column sums: block owns 4 consecutive float4 columns
    const int c  = tid & 3;
    const int g  = tid >> 2;                 // 64 b-groups
    const int c4 = blockIdx.x * 4 + c;
    const float4* __restrict__ p = (const float4*)partial;
    float4 acc = make_float4(0.f, 0.f, 0.f, 0.f);
    for (int b = g; b < NCB; b += 64) {
        const float w = wb[b];
        float4 v = p[(size_t)b * (Q / 4) + c4];
        acc.x = fmaf(w, v.x, acc.x); acc.y = fmaf(w, v.y, acc.y);
        acc.z = fmaf(w, v.z, acc.z); acc.w = fmaf(w, v.w, acc.w);
    }
    sacc[g][c] = acc;
    __syncthreads();
    if (g == 0) {   // threads 0..3
        float4 t = sacc[0][c];
        #pragma unroll
        for (int gg = 1; gg < 64; ++gg) {
            float4 u = sacc[gg][c];
            t.x += u.x; t.y += u.y; t.z += u.z; t.w += u.w;
        }
        t.x *= invZ; t.y *= invZ; t.z *= invZ; t.w *= invZ;
        ((float4*)s_t)[c4] = t;
    }
}

// ---------------------------------------------------------------------------
// K3: out[i] = out1[i] + Kw[i, Q:2Q] . s_t   (one wave per row, no barriers)
// ---------------------------------------------------------------------------
__global__ __launch_bounds__(256) void k3_kernel(
    const float* __restrict__ Kw, const float* __restrict__ s_t,
    const float* __restrict__ out1, float* __restrict__ out)
{
    const int lane = threadIdx.x & 63;
    const int wid  = threadIdx.x >> 6;
    const int i = blockIdx.x * 4 + wid;
    const float4* __restrict__ row = (const float4*)(Kw + (size_t)i * (2 * Q) + Q);
    const float4* __restrict__ sg  = (const float4*)s_t;
    float a0 = 0.f, a1 = 0.f, a2 = 0.f, a3 = 0.f;
    #pragma unroll
    for (int c = 0; c < 16; c += 4) {
        float4 x0 = row[(c + 0) * 64 + lane], y0 = sg[(c + 0) * 64 + lane];
        float4 x1 = row[(c + 1) * 64 + lane], y1 = sg[(c + 1) * 64 + lane];
        float4 x2 = row[(c + 2) * 64 + lane], y2 = sg[(c + 2) * 64 + lane];
        float4 x3 = row[(c + 3) * 64 + lane], y3 = sg[(c + 3) * 64 + lane];
        a0 = fmaf(x0.x, y0.x, a0); a0 = fmaf(x0.y, y0.y, a0);
        a0 = fmaf(x0.z, y0.z, a0); a0 = fmaf(x0.w, y0.w, a0);
        a1 = fmaf(x1.x, y1.x, a1); a1 = fmaf(x1.y, y1.y, a1);
        a1 = fmaf(x1.z, y1.z, a1); a1 = fmaf(x1.w, y1.w, a1);
        a2 = fmaf(x2.x, y2.x, a2); a2 = fmaf(x2.y, y2.y, a2);
        a2 = fmaf(x2.z, y2.z, a2); a2 = fmaf(x2.w, y2.w, a2);
        a3 = fmaf(x3.x, y3.x, a3); a3 = fmaf(x3.y, y3.y, a3);
        a3 = fmaf(x3.z, y3.z, a3); a3 = fmaf(x3.w, y3.w, a3);
    }
    float d = (a0 + a1) + (a2 + a3);
    #pragma unroll
    for (int off = 32; off > 0; off >>= 1) d += __shfl_down(d, off, 64);
    if (lane == 0) out[i] = out1[i] + d;
}

// ---------------------------------------------------------------------------
extern "C" void kernel_launch(void* const* d_in, const int* in_sizes, int n_in,
                              void* d_out, int out_size, void* d_ws, size_t ws_size,
                              hipStream_t stream)
{
    const float* query = (const float*)d_in[0];   // [Q]
    const float* ctx   = (const float*)d_in[1];   // [L, Q]
    const float* Kw    = (const float*)d_in[2];   // [Q, 2Q]
    float* out = (float*)d_out;                   // [Q]

    // workspace layout (floats); ws is >= 512 MB per harness poison size
    float* ws      = (float*)d_ws;
    float* score   = ws;                          // L          = 8192
    float* out1    = ws + L;                      // Q          = 4096
    float* s_t     = ws + L + Q;                  // Q          = 4096
    float* partial = ws + L + 2 * Q;              // NCB*Q      = 32 MiB

    k1_kernel<<<NCB + NKB, 256, 0, stream>>>(query, ctx, Kw, partial, score, out1);
    k2_kernel<<<Q / 4 / 4, 256, 0, stream>>>(partial, score, s_t);
    k3_kernel<<<Q / 4, 256, 0, stream>>>(Kw, s_t, out1, out);
}